// Round 10
// baseline (136.326 us; speedup 1.0000x reference)
//
#include <hip/hip_runtime.h>
#include <hip/hip_bf16.h>
#include <stdint.h>

typedef __attribute__((ext_vector_type(8))) short short8;
typedef __attribute__((ext_vector_type(4))) float f32x4;

#define B_   16
#define C_   64
#define H_   112
#define W_   112
#define O_   128
#define HP   114
#define HWP  (HP*HP)          // 12996 padded plane positions
#define HW   (H_*W_)          // 12544
#define XPAD_BYTES ((size_t)B_*HWP*C_*2)   // 26,615,808
#define NROWS 368             // staged rows per buffer (union needs 362)

__device__ __forceinline__ unsigned short f2bf(float f) {
    union { float f; uint32_t u; } v; v.f = f;
    uint32_t u = v.u;
    u += 0x7fffu + ((u >> 16) & 1u);   // round-to-nearest-even
    return (unsigned short)(u >> 16);
}

// ---------------- Pass 0 (fused): pad-transpose + weight re-layout ----------------
__global__ void prep(const float* __restrict__ x, const float* __restrict__ wt,
                     unsigned short* __restrict__ xpad,
                     unsigned short* __restrict__ wbuf)
{
    const int t = threadIdx.x;
    if (blockIdx.x >= B_ * H_) {
        // weight re-layout [s][ks][wc][nf][lane][j]: 1KB-coalesced B-fragments
        int f = (blockIdx.x - B_ * H_) * 256 + t;  // [0, 73728)
        int j    = f & 7;
        int lane = (f >> 3) & 63;
        int nf   = (f >> 9) & 3;
        int wc   = (f >> 11) & 1;
        int ks   = (f >> 12) & 1;
        int s    = f >> 13;
        int o = wc * 64 + nf * 16 + (lane & 15);
        int c = (ks * 4 + (lane >> 4)) * 8 + j;
        int kh = s / 3, kw = s % 3;
        wbuf[f] = f2bf(wt[(((size_t)c * 3 + kh) * 3 + kw) * O_ + o]);
        return;
    }

    __shared__ float tile[64][114];   // stride 114: 8B-aligned float2 writes
    const int bh = blockIdx.x;
    const int b = bh / H_, h = bh % H_;

    const float* xr = x + ((size_t)b * C_ * HW) + (size_t)h * W_;  // x[b][0][h][0]
    #pragma unroll
    for (int i = 0; i < 7; ++i) {                  // 64c * 28w4 = 1792 = 7*256
        int flat = i * 256 + t;
        int c = flat / 28, w4 = flat % 28;
        f32x4 v = __builtin_nontemporal_load(
            (const f32x4*)(xr + (size_t)c * HW + (size_t)w4 * 4));
        *(float2*)&tile[c][w4 * 4]     = make_float2(v.x, v.y);
        *(float2*)&tile[c][w4 * 4 + 2] = make_float2(v.z, v.w);
    }

    // Border zeroing (disjoint from interior writes):
    if (t < 64) {
        size_t base = ((size_t)(b * HP + h + 1) * HP) * 64;
        xpad[base + t] = 0;                        // (h+1, 0, ch t)
        xpad[base + (size_t)113 * 64 + t] = 0;     // (h+1, 113, ch t)
    }
    if (h == 0 || h == 111) {                      // full top/bottom halo rows
        const int row = (h == 0) ? 0 : 113;
        size_t base = ((size_t)(b * HP + row) * HP) * 64;
        ushort4 z4; z4.x = z4.y = z4.z = z4.w = 0;
        for (int k = t; k < (HP * 64) / 4; k += 256)
            *(ushort4*)(xpad + base + (size_t)k * 4) = z4;
    }
    __syncthreads();

    unsigned short* dst = xpad + ((size_t)(b * HP + h + 1) * HP + 1) * C_;  // (b,h+1,1,0)
    #pragma unroll
    for (int j = 0; j < 7; ++j) {                  // 112w * 16 c4 = 1792 = 7*256
        int flat = j * 256 + t;
        int w = flat >> 4, c = (flat & 15) * 4;
        ushort4 v;
        v.x = f2bf(tile[c + 0][w]);
        v.y = f2bf(tile[c + 1][w]);
        v.z = f2bf(tile[c + 2][w]);
        v.w = f2bf(tile[c + 3][w]);
        *(ushort4*)(dst + (size_t)w * C_ + c) = v;
    }
}

// ---------------- Pass 1: PERSISTENT double-buffered implicit-GEMM conv ----------
// 256 blocks x 512 threads, 1 block/CU, 6-7 tiles each (XCD-contiguous).
// Loop: sync -> issue stage(t+1 -> other 46KB buffer) -> compute(t) -> store(t).
// Next tile's staging drains under current tile's compute+store; stores drain
// under the next stage. Reader swizzle / wbuf addressing / epilogue layout are
// byte-identical to the verified R4 kernel (bank conflicts measured 0).
__global__ __launch_bounds__(512, 2) void conv_gemm(
    const char* __restrict__ xpad,
    const char* __restrict__ wbuf,
    float* __restrict__ out)
{
    __shared__ char lds[2][NROWS * 128];   // 2 x 47104 = 94208 B

    const int t = threadIdx.x;
    const int lane = t & 63, wid = t >> 6;
    const int wr = wid >> 1, wc = wid & 1;   // M-quarter (32 rows), N-half (64 cols)
    const int p = blockIdx.x;                // 0..255
    const int xcd = p & 7, slot = p >> 3;    // 8 XCDs x 32 slots
    const int ntiles = (slot < 4) ? 7 : 6;   // 196 = 6*32 + 4 per XCD
    const int kq = lane >> 4;

    // ---- stage tile g's 368-row union into buf (linear dest, pre-XOR source)
    auto stage = [&](char* buf, int g) {
        const int ml0r = (g % 98) * 128;
        const int pb = ml0r + 2 * (ml0r / W_);
        const char* plane = xpad + (size_t)(g / 98) * ((size_t)HWP * 128);
        #pragma unroll
        for (int i = 0; i < 6; ++i) {
            if (i < 5 || wid < 6) {              // 2944 units, wave-uniform guard
                const int gb = i * 512 + wid * 64;
                const int u = gb + lane;
                const int r = u >> 3, ck = u & 7;
                __builtin_amdgcn_global_load_lds(
                    (const __attribute__((address_space(1))) void*)
                        (plane + (size_t)(pb + r) * 128 + ((ck ^ (r & 7)) << 4)),
                    (__attribute__((address_space(3))) void*)(buf + gb * 16),
                    16, 0, 0);
            }
        }
    };

    int g = xcd * 196 + slot;
    stage(lds[0], g);

    for (int j = 0; j < ntiles; ++j, g += 32) {
        const int b = g / 98;
        const int ml0 = (g % 98) * 128;
        const int pbase = ml0 + 2 * (ml0 / W_);

        __syncthreads();                          // buf[j&1] staged & visible
        if (j + 1 < ntiles) stage(lds[(j + 1) & 1], g + 32);
        const char* A = lds[j & 1];

        int rowb[2];
        #pragma unroll
        for (int mf = 0; mf < 2; ++mf) {
            int ml = ml0 + wr * 32 + mf * 16 + (lane & 15);
            rowb[mf] = ml + 2 * (ml / W_) - pbase;
        }

        f32x4 acc[2][4] = {};

        #pragma unroll
        for (int s = 0; s < 9; ++s) {
            const int soff = (s / 3) * HP + (s % 3);
            const char* wb = wbuf + s * 16384 + wc * 4096 + lane * 16;

            #pragma unroll
            for (int ks = 0; ks < 2; ++ks) {
                short8 bv[4];
                #pragma unroll
                for (int nf = 0; nf < 4; ++nf)
                    bv[nf] = *(const short8*)(wb + ks * 8192 + nf * 1024);

                short8 av[2];
                #pragma unroll
                for (int mf = 0; mf < 2; ++mf) {
                    const int lrow = rowb[mf] + soff;
                    const int ck = (ks * 4 + kq) ^ (lrow & 7);
                    av[mf] = *(const short8*)(A + lrow * 128 + (ck << 4));
                }
                __builtin_amdgcn_s_setprio(1);
                #pragma unroll
                for (int mf = 0; mf < 2; ++mf)
                    #pragma unroll
                    for (int nf = 0; nf < 4; ++nf)
                        acc[mf][nf] = __builtin_amdgcn_mfma_f32_16x16x32_bf16(
                            av[mf], bv[nf], acc[mf][nf], 0, 0, 0);
                __builtin_amdgcn_s_setprio(0);
            }
        }

        // Epilogue: C/D col=lane&15 (o), row=(lane>>4)*4+reg (m); f32x4 to NCHW.
        const int oc = wc * 64 + (lane & 15);
        const int mrow = ml0 + wr * 32 + ((lane >> 4) << 2);
        #pragma unroll
        for (int mf = 0; mf < 2; ++mf) {
            #pragma unroll
            for (int nf = 0; nf < 4; ++nf) {
                float* dst = out + ((size_t)(b * O_ + oc + nf * 16) * HW)
                           + mrow + mf * 16;
                *(f32x4*)dst = acc[mf][nf];
            }
        }
    }
}

extern "C" void kernel_launch(void* const* d_in, const int* in_sizes, int n_in,
                              void* d_out, int out_size, void* d_ws, size_t ws_size,
                              hipStream_t stream) {
    const float* x  = (const float*)d_in[0];
    const float* wt = (const float*)d_in[1];
    float* out = (float*)d_out;
    char* xpad = (char*)d_ws;
    char* wbuf = (char*)d_ws + XPAD_BYTES;

    hipLaunchKernelGGL(prep, dim3(B_ * H_ + 288), dim3(256), 0, stream,
                       x, wt, (unsigned short*)xpad, (unsigned short*)wbuf);
    hipLaunchKernelGGL(conv_gemm, dim3(256), dim3(512), 0, stream,
                       xpad, wbuf, out);
}

// Round 11
// 105.557 us; speedup vs baseline: 1.2915x; 1.2915x over previous
//
#include <hip/hip_runtime.h>
#include <hip/hip_bf16.h>
#include <stdint.h>

typedef __attribute__((ext_vector_type(8))) short short8;
typedef __attribute__((ext_vector_type(4))) float f32x4;

#define B_   16
#define C_   64
#define H_   112
#define W_   112
#define O_   128
#define HP   114
#define HWP  (HP*HP)          // 12996 padded plane positions
#define HW   (H_*W_)          // 12544
#define XPAD_BYTES ((size_t)B_*HWP*C_*2)   // 26,615,808

__device__ __forceinline__ unsigned short f2bf(float f) {
    union { float f; uint32_t u; } v; v.f = f;
    uint32_t u = v.u;
    u += 0x7fffu + ((u >> 16) & 1u);   // round-to-nearest-even
    return (unsigned short)(u >> 16);
}

// ---------------- Pass 0 (fused): pad-transpose + weight re-layout ----------------
__global__ void prep(const float* __restrict__ x, const float* __restrict__ wt,
                     unsigned short* __restrict__ xpad,
                     unsigned short* __restrict__ wbuf)
{
    const int t = threadIdx.x;
    if (blockIdx.x >= B_ * H_) {
        // weight re-layout [s][ks][wc][nf][lane][j]: 1KB-coalesced B-fragments
        int f = (blockIdx.x - B_ * H_) * 256 + t;  // [0, 73728)
        int j    = f & 7;
        int lane = (f >> 3) & 63;
        int nf   = (f >> 9) & 3;
        int wc   = (f >> 11) & 1;
        int ks   = (f >> 12) & 1;
        int s    = f >> 13;
        int o = wc * 64 + nf * 16 + (lane & 15);
        int c = (ks * 4 + (lane >> 4)) * 8 + j;
        int kh = s / 3, kw = s % 3;
        wbuf[f] = f2bf(wt[(((size_t)c * 3 + kh) * 3 + kw) * O_ + o]);
        return;
    }

    __shared__ float tile[64][114];   // stride 114: 8B-aligned float2 writes
    const int bh = blockIdx.x;
    const int b = bh / H_, h = bh % H_;

    const float* xr = x + ((size_t)b * C_ * HW) + (size_t)h * W_;  // x[b][0][h][0]
    #pragma unroll
    for (int i = 0; i < 7; ++i) {                  // 64c * 28w4 = 1792 = 7*256
        int flat = i * 256 + t;
        int c = flat / 28, w4 = flat % 28;
        f32x4 v = __builtin_nontemporal_load(
            (const f32x4*)(xr + (size_t)c * HW + (size_t)w4 * 4));
        *(float2*)&tile[c][w4 * 4]     = make_float2(v.x, v.y);
        *(float2*)&tile[c][w4 * 4 + 2] = make_float2(v.z, v.w);
    }

    // Border zeroing (disjoint from interior writes):
    if (t < 64) {
        size_t base = ((size_t)(b * HP + h + 1) * HP) * 64;
        xpad[base + t] = 0;                        // (h+1, 0, ch t)
        xpad[base + (size_t)113 * 64 + t] = 0;     // (h+1, 113, ch t)
    }
    if (h == 0 || h == 111) {                      // full top/bottom halo rows
        const int row = (h == 0) ? 0 : 113;
        size_t base = ((size_t)(b * HP + row) * HP) * 64;
        ushort4 z4; z4.x = z4.y = z4.z = z4.w = 0;
        for (int k = t; k < (HP * 64) / 4; k += 256)
            *(ushort4*)(xpad + base + (size_t)k * 4) = z4;
    }
    __syncthreads();

    unsigned short* dst = xpad + ((size_t)(b * HP + h + 1) * HP + 1) * C_;  // (b,h+1,1,0)
    #pragma unroll
    for (int j = 0; j < 7; ++j) {                  // 112w * 16 c4 = 1792 = 7*256
        int flat = j * 256 + t;
        int w = flat >> 4, c = (flat & 15) * 4;
        ushort4 v;
        v.x = f2bf(tile[c + 0][w]);
        v.y = f2bf(tile[c + 1][w]);
        v.z = f2bf(tile[c + 2][w]);
        v.w = f2bf(tile[c + 3][w]);
        *(ushort4*)(dst + (size_t)w * C_ + c) = v;
    }
}

// ---------------- Pass 1: ZERO-LDS L2-streaming implicit-GEMM conv ----------------
// A-fragments load straight from L2-resident xpad (same ~16 sectors/instr as the
// staged path delivered), B from fragment-ordered wbuf. No LDS, no barriers, no
// stage-drain; 4 blocks/CU = 16 waves/CU hide L2 latency. Operand bytes are
// byte-identical to the verified R4 path (unswizzle identity).
__global__ __launch_bounds__(256, 4) void conv_gemm(
    const char* __restrict__ xpad,
    const char* __restrict__ wbuf,
    float* __restrict__ out)
{
    const int t = threadIdx.x;
    const int lane = t & 63, wid = t >> 6;
    const int wr = wid >> 1, wc = wid & 1;
    const int bid0 = blockIdx.x;
    const int bid = (bid0 & 7) * 196 + (bid0 >> 3);  // XCD swizzle, 1568 = 8*196 exact
    const int b = bid / 98;                 // 98 M-tiles per batch, exact
    const int ml0 = (bid % 98) * 128;
    const int kq = lane >> 4;               // k-quarter 0..3

    const char* plane = xpad + (size_t)b * ((size_t)HWP * 128);

    // Per-lane, per-mf A base: k-octet kq of padded row (ml + 2*oh); the K-loop
    // adds soff*128 + ks*64.  A[ml][c] == xpad[b][ml+2*oh+soff][c] for c-window.
    const char* abase[4];
    #pragma unroll
    for (int mf = 0; mf < 4; ++mf) {
        int ml = ml0 + wr * 64 + mf * 16 + (lane & 15);
        int oh = ml / W_;
        abase[mf] = plane + (size_t)(ml + 2 * oh) * 128 + (kq << 4);
    }
    const char* wb0 = wbuf + wc * 4096 + lane * 16;

    f32x4 acc[4][4] = {};

    #pragma unroll 1
    for (int s = 0; s < 9; ++s) {
        const int aoff = ((s / 3) * HP + (s % 3)) * 128;
        const char* wb = wb0 + s * 16384;

        #pragma unroll
        for (int ks = 0; ks < 2; ++ks) {
            short8 bv[4], av[4];
            #pragma unroll
            for (int nf = 0; nf < 4; ++nf)
                bv[nf] = *(const short8*)(wb + ks * 8192 + nf * 1024);
            #pragma unroll
            for (int mf = 0; mf < 4; ++mf)
                av[mf] = *(const short8*)(abase[mf] + aoff + ks * 64);

            __builtin_amdgcn_s_setprio(1);
            #pragma unroll
            for (int mf = 0; mf < 4; ++mf)
                #pragma unroll
                for (int nf = 0; nf < 4; ++nf)
                    acc[mf][nf] = __builtin_amdgcn_mfma_f32_16x16x32_bf16(
                        av[mf], bv[nf], acc[mf][nf], 0, 0, 0);
            __builtin_amdgcn_s_setprio(0);
        }
    }

    // Epilogue: C/D layout col=lane&15 (o), row=(lane>>4)*4+reg (m).
    const int oc = wc * 64 + (lane & 15);
    const int mrow = ml0 + wr * 64 + ((lane >> 4) << 2);
    #pragma unroll
    for (int mf = 0; mf < 4; ++mf) {
        #pragma unroll
        for (int nf = 0; nf < 4; ++nf) {
            float* dst = out + ((size_t)(b * O_ + oc + nf * 16) * HW) + mrow + mf * 16;
            *(f32x4*)dst = acc[mf][nf];
        }
    }
}

extern "C" void kernel_launch(void* const* d_in, const int* in_sizes, int n_in,
                              void* d_out, int out_size, void* d_ws, size_t ws_size,
                              hipStream_t stream) {
    const float* x  = (const float*)d_in[0];
    const float* wt = (const float*)d_in[1];
    float* out = (float*)d_out;
    char* xpad = (char*)d_ws;
    char* wbuf = (char*)d_ws + XPAD_BYTES;

    hipLaunchKernelGGL(prep, dim3(B_ * H_ + 288), dim3(256), 0, stream,
                       x, wt, (unsigned short*)xpad, (unsigned short*)wbuf);
    hipLaunchKernelGGL(conv_gemm, dim3(1568), dim3(256), 0, stream,
                       xpad, wbuf, out);
}

// Round 12
// 65.860 us; speedup vs baseline: 2.0699x; 1.6028x over previous
//
#include <hip/hip_runtime.h>
#include <hip/hip_bf16.h>
#include <stdint.h>

typedef __attribute__((ext_vector_type(8))) short short8;
typedef __attribute__((ext_vector_type(4))) float f32x4;

#define B_   16
#define C_   64
#define H_   112
#define W_   112
#define O_   128
#define HP   114
#define HWP  (HP*HP)          // 12996 padded plane positions
#define HW   (H_*W_)          // 12544
#define XPAD_BYTES ((size_t)B_*HWP*C_*2)   // 26,615,808
#define CROWS 136             // rows per kh-chunk (need 134; 136 -> wave-uniform tail)

__device__ __forceinline__ unsigned short f2bf(float f) {
    union { float f; uint32_t u; } v; v.f = f;
    uint32_t u = v.u;
    u += 0x7fffu + ((u >> 16) & 1u);   // round-to-nearest-even
    return (unsigned short)(u >> 16);
}

// ---------------- Pass 0 (fused): pad-transpose + weight re-layout ----------------
__global__ void prep(const float* __restrict__ x, const float* __restrict__ wt,
                     unsigned short* __restrict__ xpad,
                     unsigned short* __restrict__ wbuf)
{
    const int t = threadIdx.x;
    if (blockIdx.x >= B_ * H_) {
        // weight re-layout [s][ks][wc][nf][lane][j]: 1KB-coalesced B-fragments
        int f = (blockIdx.x - B_ * H_) * 256 + t;  // [0, 73728)
        int j    = f & 7;
        int lane = (f >> 3) & 63;
        int nf   = (f >> 9) & 3;
        int wc   = (f >> 11) & 1;
        int ks   = (f >> 12) & 1;
        int s    = f >> 13;
        int o = wc * 64 + nf * 16 + (lane & 15);
        int c = (ks * 4 + (lane >> 4)) * 8 + j;
        int kh = s / 3, kw = s % 3;
        wbuf[f] = f2bf(wt[(((size_t)c * 3 + kh) * 3 + kw) * O_ + o]);
        return;
    }

    __shared__ float tile[64][114];   // stride 114: 8B-aligned float2 writes
    const int bh = blockIdx.x;
    const int b = bh / H_, h = bh % H_;

    const float* xr = x + ((size_t)b * C_ * HW) + (size_t)h * W_;  // x[b][0][h][0]
    #pragma unroll
    for (int i = 0; i < 7; ++i) {                  // 64c * 28w4 = 1792 = 7*256
        int flat = i * 256 + t;
        int c = flat / 28, w4 = flat % 28;
        f32x4 v = __builtin_nontemporal_load(
            (const f32x4*)(xr + (size_t)c * HW + (size_t)w4 * 4));
        *(float2*)&tile[c][w4 * 4]     = make_float2(v.x, v.y);
        *(float2*)&tile[c][w4 * 4 + 2] = make_float2(v.z, v.w);
    }

    // Border zeroing (disjoint from interior writes):
    if (t < 64) {
        size_t base = ((size_t)(b * HP + h + 1) * HP) * 64;
        xpad[base + t] = 0;                        // (h+1, 0, ch t)
        xpad[base + (size_t)113 * 64 + t] = 0;     // (h+1, 113, ch t)
    }
    if (h == 0 || h == 111) {                      // full top/bottom halo rows
        const int row = (h == 0) ? 0 : 113;
        size_t base = ((size_t)(b * HP + row) * HP) * 64;
        ushort4 z4; z4.x = z4.y = z4.z = z4.w = 0;
        for (int k = t; k < (HP * 64) / 4; k += 256)
            *(ushort4*)(xpad + base + (size_t)k * 4) = z4;
    }
    __syncthreads();

    unsigned short* dst = xpad + ((size_t)(b * HP + h + 1) * HP + 1) * C_;  // (b,h+1,1,0)
    #pragma unroll
    for (int j = 0; j < 7; ++j) {                  // 112w * 16 c4 = 1792 = 7*256
        int flat = j * 256 + t;
        int w = flat >> 4, c = (flat & 15) * 4;
        ushort4 v;
        v.x = f2bf(tile[c + 0][w]);
        v.y = f2bf(tile[c + 1][w]);
        v.z = f2bf(tile[c + 2][w]);
        v.w = f2bf(tile[c + 3][w]);
        *(ushort4*)(dst + (size_t)w * C_ + c) = v;
    }
}

// ---------------- Pass 1: implicit-GEMM conv, 3-chunk counted-vmcnt pipeline ------
// A-union split into 3 kh-chunks (134 rows each, disjoint LDS buffers). All 15
// stage loads issued up-front; per chunk: counted vmcnt (chunk loads are the
// FIFO-oldest, so the count is safe vs interleaved B-loads) + raw s_barrier
// (no vmcnt(0) drain) + sched_barrier, then 96 MFMAs. Chunks 1/2 stream in
// under chunk 0/1 compute. Reader swizzle / epilogue identical to R4 (verified).
__global__ __launch_bounds__(256, 3) void conv_gemm(
    const char* __restrict__ xpad,
    const char* __restrict__ wbuf,
    float* __restrict__ out)
{
    __shared__ char ldsA[3][CROWS * 128];   // 3 x 17408 = 52224 B -> 3 blocks/CU

    const int t = threadIdx.x;
    const int lane = t & 63, wid = t >> 6;
    const int wr = wid >> 1, wc = wid & 1;
    const int bid0 = blockIdx.x;
    const int bid = (bid0 & 7) * 196 + (bid0 >> 3);  // XCD swizzle, 1568 = 8*196 exact
    const int b = bid / 98;                 // 98 M-tiles per batch, exact
    const int ml0 = (bid % 98) * 128;
    const int pbase = ml0 + 2 * (ml0 / W_); // first padded-plane row of the union
    const int kq = lane >> 4;

    // ---- issue ALL chunk stages up-front (chunk c = padded rows pbase+c*114+[0,136))
    // wave0: 5 issues/chunk, waves1-3: 4 (1088 units = 4.25*256). Linear LDS dest,
    // source chunk pre-XORed by local row (rule #21 involution).
    const char* plane = xpad + (size_t)b * ((size_t)HWP * 128);
    #pragma unroll
    for (int c = 0; c < 3; ++c) {
        const char* src = plane + (size_t)(pbase + c * 114) * 128;
        #pragma unroll
        for (int i = 0; i < 5; ++i) {
            if (i < 4 || wid == 0) {                 // wave-uniform guard
                const int gb = (i < 4) ? (i * 256 + wid * 64) : 1024;
                const int u = gb + lane;
                const int r = u >> 3, ck = u & 7;
                __builtin_amdgcn_global_load_lds(
                    (const __attribute__((address_space(1))) void*)
                        (src + (size_t)r * 128 + ((ck ^ (r & 7)) << 4)),
                    (__attribute__((address_space(3))) void*)(&ldsA[c][0] + gb * 16),
                    16, 0, 0);
            }
        }
    }

    // Per-fragment chunk-local base rows: rowb = ml + 2*oh - pbase in [0,131];
    // chunk offset c*114 cancels between soff and chunk base.
    int rowb[4];
    #pragma unroll
    for (int mf = 0; mf < 4; ++mf) {
        int ml = ml0 + wr * 64 + mf * 16 + (lane & 15);
        rowb[mf] = ml + 2 * (ml / W_) - pbase;
    }

    f32x4 acc[4][4] = {};

    #define CHUNK(c, vm)                                                         \
    {                                                                            \
        asm volatile("s_waitcnt vmcnt(" #vm ")" ::: "memory");                   \
        __builtin_amdgcn_s_barrier();                                            \
        __builtin_amdgcn_sched_barrier(0);                                       \
        const char* A = &ldsA[c][0];                                             \
        _Pragma("unroll")                                                        \
        for (int kw = 0; kw < 3; ++kw) {                                         \
            const char* wb = wbuf + ((c) * 3 + kw) * 16384 + wc * 4096 + lane*16;\
            _Pragma("unroll")                                                    \
            for (int ks = 0; ks < 2; ++ks) {                                     \
                short8 bv[4], av[4];                                             \
                _Pragma("unroll")                                                \
                for (int nf = 0; nf < 4; ++nf)                                   \
                    bv[nf] = *(const short8*)(wb + ks * 8192 + nf * 1024);       \
                _Pragma("unroll")                                                \
                for (int mf = 0; mf < 4; ++mf) {                                 \
                    const int lr = rowb[mf] + kw;                                \
                    const int ck2 = (ks * 4 + kq) ^ (lr & 7);                    \
                    av[mf] = *(const short8*)(A + lr * 128 + (ck2 << 4));        \
                }                                                                \
                __builtin_amdgcn_s_setprio(1);                                   \
                _Pragma("unroll")                                                \
                for (int mf = 0; mf < 4; ++mf)                                   \
                    _Pragma("unroll")                                            \
                    for (int nf = 0; nf < 4; ++nf)                               \
                        acc[mf][nf] = __builtin_amdgcn_mfma_f32_16x16x32_bf16(   \
                            av[mf], bv[nf], acc[mf][nf], 0, 0, 0);               \
                __builtin_amdgcn_s_setprio(0);                                   \
            }                                                                    \
        }                                                                        \
    }
    CHUNK(0, 8)   // chunk0 loads (oldest 4-5/wave) complete; chunks 1,2 in flight
    CHUNK(1, 4)   // chunk1 complete; chunk2 still in flight
    CHUNK(2, 0)   // full drain
    #undef CHUNK

    // Epilogue: C/D layout col=lane&15 (o), row=(lane>>4)*4+reg (m).
    const int oc = wc * 64 + (lane & 15);
    const int mrow = ml0 + wr * 64 + ((lane >> 4) << 2);
    #pragma unroll
    for (int mf = 0; mf < 4; ++mf) {
        #pragma unroll
        for (int nf = 0; nf < 4; ++nf) {
            float* dst = out + ((size_t)(b * O_ + oc + nf * 16) * HW) + mrow + mf * 16;
            *(f32x4*)dst = acc[mf][nf];
        }
    }
}

extern "C" void kernel_launch(void* const* d_in, const int* in_sizes, int n_in,
                              void* d_out, int out_size, void* d_ws, size_t ws_size,
                              hipStream_t stream) {
    const float* x  = (const float*)d_in[0];
    const float* wt = (const float*)d_in[1];
    float* out = (float*)d_out;
    char* xpad = (char*)d_ws;
    char* wbuf = (char*)d_ws + XPAD_BYTES;

    hipLaunchKernelGGL(prep, dim3(B_ * H_ + 288), dim3(256), 0, stream,
                       x, wt, (unsigned short*)xpad, (unsigned short*)wbuf);
    hipLaunchKernelGGL(conv_gemm, dim3(1568), dim3(256), 0, stream,
                       xpad, (const char*)wbuf, out);
}